// Round 1
// baseline (263.978 us; speedup 1.0000x reference)
//
#include <hip/hip_runtime.h>

// Spatially-varying 19x19 blur, reflect padding 9.
// out[b,c,i,j] = (1/361) * sum_{u,v} xpad[b,c,i+u,j+v] * kernel[b,u*19+v,i,j]
// Shapes: x[2,3,256,256] f32, kernel[2,361,256,256] f32, out[2,3,256,256] f32.
// Memory-bound on the 189 MB kernel tensor (read once, no reuse).

#define LW     19
#define PAD    9
#define K2     361
#define HH     256
#define WW     256
#define CC     3
#define TILE_W 64
#define TILE_H 4
#define SM_W   (TILE_W + LW - 1)   // 82
#define SM_H   (TILE_H + LW - 1)   // 22

__global__ __launch_bounds__(256)
void svblur_kernel(const float* __restrict__ x,
                   const float* __restrict__ ker,
                   float* __restrict__ out) {
    __shared__ float tile[CC][SM_H][SM_W];   // 3*22*82*4 = 21648 B

    const int tx  = threadIdx.x;             // 0..63  (j within tile)
    const int ty  = threadIdx.y;             // 0..3   (i within tile)
    const int tid = ty * TILE_W + tx;        // 0..255
    const int j0  = blockIdx.x * TILE_W;
    const int i0  = blockIdx.y * TILE_H;
    const int b   = blockIdx.z;

    // ---- stage reflect-padded input tile into LDS ----
    const float* xb = x + (size_t)b * CC * HH * WW;
    for (int idx = tid; idx < CC * SM_H * SM_W; idx += 256) {
        int c  = idx / (SM_H * SM_W);
        int rm = idx - c * (SM_H * SM_W);
        int r  = rm / SM_W;
        int cc = rm - r * SM_W;
        int gr = i0 + r - PAD;
        gr = gr < 0 ? -gr : (gr >= HH ? 2 * HH - 2 - gr : gr);
        int gc = j0 + cc - PAD;
        gc = gc < 0 ? -gc : (gc >= WW ? 2 * WW - 2 - gc : gc);
        ((float*)tile)[idx] = xb[((size_t)c * HH + gr) * WW + gc];
    }
    __syncthreads();

    // ---- main loop: stream kernel taps, accumulate 3 channels ----
    const int i = i0 + ty;
    const int j = j0 + tx;
    const float* kp = ker + ((size_t)b * K2 * HH + i) * WW + j;   // advances by H*W per tap

    float a0 = 0.f, a1 = 0.f, a2 = 0.f;
    for (int u = 0; u < LW; ++u) {
        const float* r0 = &tile[0][ty + u][tx];
        const float* r1 = &tile[1][ty + u][tx];
        const float* r2 = &tile[2][ty + u][tx];
        const float* kq = kp + (size_t)(u * LW) * (HH * WW);
        #pragma unroll
        for (int v = 0; v < LW; ++v) {
            float kv = kq[(size_t)v * (HH * WW)];   // coalesced: lanes are consecutive j
            a0 = fmaf(r0[v], kv, a0);
            a1 = fmaf(r1[v], kv, a1);
            a2 = fmaf(r2[v], kv, a2);
        }
    }

    const float s = 1.0f / (float)K2;
    float* op = out + (((size_t)b * CC) * HH + i) * WW + j;
    op[0 * (HH * WW)] = a0 * s;
    op[1 * (HH * WW)] = a1 * s;
    op[2 * (HH * WW)] = a2 * s;
}

extern "C" void kernel_launch(void* const* d_in, const int* in_sizes, int n_in,
                              void* d_out, int out_size, void* d_ws, size_t ws_size,
                              hipStream_t stream) {
    const float* x   = (const float*)d_in[0];   // [2,3,256,256]
    const float* ker = (const float*)d_in[1];   // [2,361,256,256]
    float* out       = (float*)d_out;           // [2,3,256,256]

    dim3 grid(WW / TILE_W, HH / TILE_H, 2);     // (4, 64, 2) = 512 blocks
    dim3 block(TILE_W, TILE_H, 1);              // 256 threads
    svblur_kernel<<<grid, block, 0, stream>>>(x, ker, out);
}